// Round 5
// baseline (1153.264 us; speedup 1.0000x reference)
//
#include <hip/hip_runtime.h>

// ---------------------------------------------------------------------------
// Decoder, 5 dispatches: memset(barrier ctr) -> prep (cvt+embed) ->
// gemm_combo (gx + h0 + c0, block-role mux) -> lstm_seq (ONE persistent
// kernel, 32 steps, hand-rolled agent-scope barrier, W_hh in LDS once,
// c in registers) -> FC GEMM.
// Lessons: R2 cg::grid.sync ~60us/step (system-scope). R3/R4: per-step
// launches cost ~10us fixed each (launch + L2 flush) regardless of body;
// LDS "conflicts" on ds_read_b128 are structural, not layout.
// ---------------------------------------------------------------------------

#define B_  64
#define T_  32
#define E_  512
#define H_  1024
#define V_  10000
#define F_  2048

typedef short short8 __attribute__((ext_vector_type(8)));
typedef float floatx4 __attribute__((ext_vector_type(4)));

__device__ __forceinline__ float bf2f(unsigned short u) {
  union { unsigned int i; float f; } c; c.i = ((unsigned int)u) << 16; return c.f;
}
__device__ __forceinline__ unsigned short f2bf(float f) {
  union { float f; unsigned int i; } c; c.f = f;
  unsigned int x = c.i;
  return (unsigned short)((x + 0x7fffu + ((x >> 16) & 1u)) >> 16);
}
__device__ __forceinline__ float sigmoidf_(float x) {
  return 1.0f / (1.0f + __expf(-x));
}
// async global->LDS, 16B per lane. LDS dest = wave-uniform base + lane*16.
__device__ __forceinline__ void gl_lds16(const unsigned short* g, unsigned short* l) {
  __builtin_amdgcn_global_load_lds(
      (const __attribute__((address_space(1))) unsigned int*)g,
      (__attribute__((address_space(3))) unsigned int*)l, 16, 0, 0);
}

// ---------------- prep: fused cvt (blocks 0..4095) + embed (4096..5119) ----
#define C_WIH  524288    // 4H*E/4
#define C_WHH  1048576   // 4H*H/4
#define C_WFC  2560000   // V*H/4
#define C_WI0  524288    // H*F/4
#define C_WC0  524288
#define C_FEA  32768     // B*F/4
#define C_TOT  (C_WIH + C_WHH + C_WFC + C_WI0 + C_WC0 + C_FEA)
#define CVT_BLOCKS 4096

__global__ __launch_bounds__(256) void prep(
    const float* __restrict__ s0, const float* __restrict__ s1,
    const float* __restrict__ s2, const float* __restrict__ s3,
    const float* __restrict__ s4, const float* __restrict__ s5,
    unsigned short* __restrict__ d0, unsigned short* __restrict__ d1,
    unsigned short* __restrict__ d2, unsigned short* __restrict__ d3,
    unsigned short* __restrict__ d4, unsigned short* __restrict__ d5,
    const float* __restrict__ table, const int* __restrict__ captions,
    unsigned short* __restrict__ emb) {
  const int r = blockIdx.x;
  if (r < CVT_BLOCKS) {
    int i = r * 256 + threadIdx.x;
    const int stride = CVT_BLOCKS * 256;
    for (; i < C_TOT; i += stride) {
      const float* s; unsigned short* d; int j = i;
      if (j < C_WIH)                 { s = s0; d = d0; }
      else if ((j -= C_WIH) < C_WHH) { s = s1; d = d1; }
      else if ((j -= C_WHH) < C_WFC) { s = s2; d = d2; }
      else if ((j -= C_WFC) < C_WI0) { s = s3; d = d3; }
      else if ((j -= C_WI0) < C_WC0) { s = s4; d = d4; }
      else { j -= C_WC0; s = s5; d = d5; }
      float4 v = ((const float4*)s)[j];
      ushort4 o;
      o.x = f2bf(v.x); o.y = f2bf(v.y); o.z = f2bf(v.z); o.w = f2bf(v.w);
      ((ushort4*)d)[j] = o;
    }
  } else {
    // two embedding rows per block; 128 threads per row, 1 float4 chunk each
    int row = (r - CVT_BLOCKS) * 2 + (threadIdx.x >> 7);   // row = t*B + b
    int t = row >> 6, b = row & 63;
    int idx = captions[b * T_ + t];
    int e = threadIdx.x & 127;                              // chunk 0..127
    float4 v = ((const float4*)(table + (size_t)idx * E_))[e];
    ushort4 o;
    o.x = f2bf(v.x); o.y = f2bf(v.y); o.z = f2bf(v.z); o.w = f2bf(v.w);
    ((ushort4*)(emb + (size_t)row * E_))[e] = o;
  }
}

// ---------------- 128x128 LDS-staged bf16 MFMA GEMM body -------------------
// C = act(A @ W^T + b1 + b2). A:[M,K] bf16 rm, W:[N,K] bf16 rm. K%32==0.
template <int ACT_SIGMOID, int OUT_BF16>
__device__ __forceinline__ void gemm_body(
    unsigned short* At, unsigned short* Wt,
    const unsigned short* __restrict__ A, const unsigned short* __restrict__ W,
    const float* __restrict__ bias1, const float* __restrict__ bias2,
    void* __restrict__ out, int M, int N, int K, int m0, int n0) {
  const int tid  = threadIdx.x;
  const int lane = tid & 63;
  const int wave = tid >> 6;
  const int l15  = lane & 15;
  const int quad = lane >> 4;
  const int kb   = quad * 8;
  const int wm   = (wave >> 1) * 64;
  const int wn   = (wave & 1) * 64;

  const int c0i = tid, c1i = tid + 256;
  const int ar0 = c0i >> 2, ak0 = (c0i & 3) * 8;
  const int ar1 = c1i >> 2, ak1 = (c1i & 3) * 8;
  int am0 = m0 + ar0; if (am0 > M - 1) am0 = M - 1;
  int am1 = m0 + ar1; if (am1 > M - 1) am1 = M - 1;
  int wn0 = n0 + ar0; if (wn0 > N - 1) wn0 = N - 1;
  int wn1 = n0 + ar1; if (wn1 > N - 1) wn1 = N - 1;
  const unsigned short* Ag0 = A + (size_t)am0 * K + ak0;
  const unsigned short* Ag1 = A + (size_t)am1 * K + ak1;
  const unsigned short* Wg0 = W + (size_t)wn0 * K + ak0;
  const unsigned short* Wg1 = W + (size_t)wn1 * K + ak1;

  floatx4 acc[4][4];
#pragma unroll
  for (int i = 0; i < 4; ++i)
#pragma unroll
    for (int j = 0; j < 4; ++j) acc[i][j] = (floatx4){0.f, 0.f, 0.f, 0.f};

  for (int k0 = 0; k0 < K; k0 += 32) {
    gl_lds16(Ag0 + k0, &At[c0i * 8]);
    gl_lds16(Ag1 + k0, &At[c1i * 8]);
    gl_lds16(Wg0 + k0, &Wt[c0i * 8]);
    gl_lds16(Wg1 + k0, &Wt[c1i * 8]);
    __syncthreads();

    short8 a[4], b[4];
#pragma unroll
    for (int mt = 0; mt < 4; ++mt)
      a[mt] = *(const short8*)&At[(wm + mt * 16 + l15) * 32 + kb];
#pragma unroll
    for (int nt = 0; nt < 4; ++nt)
      b[nt] = *(const short8*)&Wt[(wn + nt * 16 + l15) * 32 + kb];
#pragma unroll
    for (int mt = 0; mt < 4; ++mt)
#pragma unroll
      for (int nt = 0; nt < 4; ++nt)
        acc[mt][nt] = __builtin_amdgcn_mfma_f32_16x16x32_bf16(a[mt], b[nt], acc[mt][nt], 0, 0, 0);
    __syncthreads();
  }

#pragma unroll
  for (int nt = 0; nt < 4; ++nt) {
    int col = n0 + wn + nt * 16 + l15;
    if (col >= N) continue;
    float bsum = (bias1 ? bias1[col] : 0.f) + (bias2 ? bias2[col] : 0.f);
#pragma unroll
    for (int mt = 0; mt < 4; ++mt) {
#pragma unroll
      for (int r = 0; r < 4; ++r) {
        int m = m0 + wm + mt * 16 + quad * 4 + r;
        if (m >= M) continue;
        float v = acc[mt][nt][r] + bsum;
        if (ACT_SIGMOID) v = sigmoidf_(v);
        if (OUT_BF16)
          ((unsigned short*)out)[(size_t)m * N + col] = f2bf(v);
        else
          ((float*)out)[(size_t)m * N + col] = v;
      }
    }
  }
}

template <int ACT_SIGMOID, int OUT_BF16>
__global__ __launch_bounds__(256) void mfma_gemm128(
    const unsigned short* __restrict__ A, const unsigned short* __restrict__ W,
    const float* __restrict__ bias1, const float* __restrict__ bias2,
    void* __restrict__ out, int M, int N, int K) {
  __shared__ unsigned short At[128 * 32];
  __shared__ unsigned short Wt[128 * 32];
  gemm_body<ACT_SIGMOID, OUT_BF16>(At, Wt, A, W, bias1, bias2, out, M, N, K,
                                   blockIdx.x * 128, blockIdx.y * 128);
}

// ---------------- combined gx + h0 + c0 GEMM dispatch ----------------------
// blocks 0..511: gx = emb @ W_ih^T + b_ih + b_hh   [2048 x 4096, K=512]
// blocks 512..519: h0 = feat @ W_init_h^T + b      [64 x 1024, K=2048] (bf16)
// blocks 520..527: c0 = feat @ W_init_c^T + b      [64 x 1024, K=2048] (f32)
__global__ __launch_bounds__(256) void gemm_combo(
    const unsigned short* __restrict__ emb, const unsigned short* __restrict__ W_ih_b,
    const float* __restrict__ b_ih, const float* __restrict__ b_hh,
    unsigned short* __restrict__ gx,
    const unsigned short* __restrict__ feat,
    const unsigned short* __restrict__ Wih0, const float* __restrict__ b_init_h,
    unsigned short* __restrict__ h0_out,
    const unsigned short* __restrict__ Wic0, const float* __restrict__ b_init_c,
    float* __restrict__ c0_out) {
  __shared__ unsigned short At[128 * 32];
  __shared__ unsigned short Wt[128 * 32];
  const int r = blockIdx.x;
  if (r < 512)
    gemm_body<0, 1>(At, Wt, emb, W_ih_b, b_ih, b_hh, (void*)gx,
                    T_ * B_, 4 * H_, E_, (r & 15) * 128, (r >> 4) * 128);
  else if (r < 520)
    gemm_body<0, 1>(At, Wt, feat, Wih0, b_init_h, (const float*)nullptr,
                    (void*)h0_out, B_, H_, F_, 0, (r - 512) * 128);
  else
    gemm_body<0, 0>(At, Wt, feat, Wic0, b_init_c, (const float*)nullptr,
                    (void*)c0_out, B_, H_, F_, 0, (r - 520) * 128);
}

// ---------------- persistent LSTM: 32 steps, hand-rolled barrier -----------
// 256 blocks x 512 thr (cooperative launch for residency guarantee; we use
// our OWN monotonic agent-scope barrier, NOT cg::grid.sync).
// Block b owns h-cols [4b,4b+4) x 4 gates = 16 W_hh rows in LDS (staged once).
// Wave w: batch-tile w&3, K-half w>>2. c state: 1 fp32 reg/thread (tid<256).
#define WSPAD 1032   // 1024 + 8 bf16 pad per row
__global__ __launch_bounds__(512, 2) void lstm_seq(
    const unsigned short* __restrict__ W_hh_b,  // [4H,H] bf16
    const unsigned short* __restrict__ gx,      // [T,B,4H] bf16 (x-part+biases)
    const float* __restrict__ c0,               // [B,H] f32
    unsigned short* __restrict__ h_all,         // [(T+1),B,H] bf16, slot0=h0
    unsigned int* __restrict__ ctr) {           // zeroed before launch
  __shared__ unsigned short Ws[16 * WSPAD];     // ~33 KB
  __shared__ float gbuf[2][B_][17];             // ~8.7 KB

  const int tid  = threadIdx.x;
  const int lane = tid & 63;
  const int wave = tid >> 6;        // 0..7
  const int l15  = lane & 15;
  const int quad = lane >> 4;
  const int kb   = quad * 8;
  const int kh   = wave >> 2;       // K half
  const int mt   = wave & 3;        // batch tile
  const int colbase = blockIdx.x * 4;

  // ---- stage 16 W_hh rows into LDS ONCE (gate-major) ----
#pragma unroll
  for (int it = 0; it < 4; ++it) {
    int row  = it * 4 + (wave >> 1);
    int half = wave & 1;
    int grow = (row >> 2) * H_ + colbase + (row & 3);
    gl_lds16(W_hh_b + (size_t)grow * H_ + half * 512 + lane * 8,
             &Ws[row * WSPAD + half * 512]);
  }

  const int cb = tid >> 2, cj = tid & 3;
  float c_reg = 0.f;
  if (tid < 256) c_reg = c0[cb * H_ + colbase + cj];
  __syncthreads();   // Ws staged (drains vmcnt)

  for (int t = 0; t < T_; ++t) {
    const unsigned short* hp = h_all + (size_t)t * B_ * H_ +
        (size_t)(mt * 16 + l15) * H_ + kh * 512 + kb;
    short8 hx[16];
#pragma unroll
    for (int i = 0; i < 16; ++i)
      hx[i] = *(const short8*)(hp + i * 32);

    float gxi = 0.f, gxf = 0.f, gxg = 0.f, gxo = 0.f;
    if (tid < 256) {
      const unsigned short* gxp = gx + ((size_t)t * B_ + cb) * (4 * H_) + colbase + cj;
      gxi = bf2f(gxp[0 * H_]);
      gxf = bf2f(gxp[1 * H_]);
      gxg = bf2f(gxp[2 * H_]);
      gxo = bf2f(gxp[3 * H_]);
    }

    floatx4 a0 = (floatx4){0,0,0,0}, a1 = a0, a2 = a0, a3 = a0;
#pragma unroll
    for (int i = 0; i < 16; i += 4) {
      short8 w0 = *(const short8*)&Ws[l15 * WSPAD + kh * 512 + kb + (i + 0) * 32];
      short8 w1 = *(const short8*)&Ws[l15 * WSPAD + kh * 512 + kb + (i + 1) * 32];
      short8 w2 = *(const short8*)&Ws[l15 * WSPAD + kh * 512 + kb + (i + 2) * 32];
      short8 w3 = *(const short8*)&Ws[l15 * WSPAD + kh * 512 + kb + (i + 3) * 32];
      a0 = __builtin_amdgcn_mfma_f32_16x16x32_bf16(hx[i + 0], w0, a0, 0, 0, 0);
      a1 = __builtin_amdgcn_mfma_f32_16x16x32_bf16(hx[i + 1], w1, a1, 0, 0, 0);
      a2 = __builtin_amdgcn_mfma_f32_16x16x32_bf16(hx[i + 2], w2, a2, 0, 0, 0);
      a3 = __builtin_amdgcn_mfma_f32_16x16x32_bf16(hx[i + 3], w3, a3, 0, 0, 0);
    }
    floatx4 acc = (a0 + a1) + (a2 + a3);

#pragma unroll
    for (int r = 0; r < 4; ++r)
      gbuf[kh][mt * 16 + quad * 4 + r][l15] = acc[r];
    __syncthreads();

    if (tid < 256) {
      float gi = gbuf[0][cb][0  + cj] + gbuf[1][cb][0  + cj] + gxi;
      float gf = gbuf[0][cb][4  + cj] + gbuf[1][cb][4  + cj] + gxf;
      float gg = gbuf[0][cb][8  + cj] + gbuf[1][cb][8  + cj] + gxg;
      float go = gbuf[0][cb][12 + cj] + gbuf[1][cb][12 + cj] + gxo;
      gi = sigmoidf_(gi);
      gf = sigmoidf_(gf);
      gg = tanhf(gg);
      go = sigmoidf_(go);
      float cn = gf * c_reg + gi * gg;
      c_reg = cn;
      h_all[(size_t)(t + 1) * B_ * H_ + cb * H_ + colbase + cj] =
          f2bf(go * tanhf(cn));
    }
    __syncthreads();   // drains h stores (vmcnt 0) + gbuf reuse safety

    // ---- monotonic agent-scope grid barrier ----
    if (tid == 0) {
      __threadfence();                       // release: L2 writeback
      atomicAdd(ctr, 1u);                    // device-scope
      unsigned tgt = (unsigned)(t + 1) * 256u;
      while (__hip_atomic_load(ctr, __ATOMIC_RELAXED, __HIP_MEMORY_SCOPE_AGENT) < tgt)
        __builtin_amdgcn_s_sleep(2);
      __threadfence();                       // acquire: L1/L2 invalidate
    }
    __syncthreads();
  }
}

// ---------------------------------------------------------------------------
extern "C" void kernel_launch(void* const* d_in, const int* in_sizes, int n_in,
                              void* d_out, int out_size, void* d_ws, size_t ws_size,
                              hipStream_t stream) {
  const float* features    = (const float*)d_in[0];
  const int*   captions    = (const int*)d_in[1];
  const float* embed_table = (const float*)d_in[2];
  const float* W_init_h    = (const float*)d_in[3];
  const float* b_init_h    = (const float*)d_in[4];
  const float* W_init_c    = (const float*)d_in[5];
  const float* b_init_c    = (const float*)d_in[6];
  const float* W_ih        = (const float*)d_in[7];
  const float* b_ih        = (const float*)d_in[8];
  const float* W_hh        = (const float*)d_in[9];
  const float* b_hh        = (const float*)d_in[10];
  const float* W_fc        = (const float*)d_in[11];
  const float* b_fc        = (const float*)d_in[12];
  float* out = (float*)d_out;

  // ---- workspace carve-up (bump allocator, 256B aligned) ----
  char* ws = (char*)d_ws;
  auto alloc = [&](size_t bytes) -> char* {
    char* p = ws;
    ws += (bytes + 255) & ~(size_t)255;
    return p;
  };
  unsigned short* W_ih_b  = (unsigned short*)alloc((size_t)4 * H_ * E_ * 2);
  unsigned short* W_hh_b  = (unsigned short*)alloc((size_t)4 * H_ * H_ * 2);
  unsigned short* W_fc_b  = (unsigned short*)alloc((size_t)V_ * H_ * 2);
  unsigned short* Wih0_b  = (unsigned short*)alloc((size_t)H_ * F_ * 2);
  unsigned short* Wic0_b  = (unsigned short*)alloc((size_t)H_ * F_ * 2);
  unsigned short* feat_b  = (unsigned short*)alloc((size_t)B_ * F_ * 2);
  unsigned short* emb_b   = (unsigned short*)alloc((size_t)T_ * B_ * E_ * 2);
  unsigned short* gx_b    = (unsigned short*)alloc((size_t)T_ * B_ * 4 * H_ * 2);
  unsigned short* h_all   = (unsigned short*)alloc((size_t)(T_ + 1) * B_ * H_ * 2);
  float*          c_f32   = (float*)alloc((size_t)B_ * H_ * 4);
  unsigned int*   ctr     = (unsigned int*)alloc(256);
  (void)ws_size; (void)in_sizes; (void)n_in; (void)out_size;

  // ---- zero the barrier counter (ws is poisoned 0xAA before every call) --
  hipMemsetAsync(ctr, 0, 256, stream);

  // ---- prep: all fp32->bf16 conversions + embedding gather (1 dispatch) --
  hipLaunchKernelGGL(prep, dim3(CVT_BLOCKS + T_ * B_ / 2), dim3(256), 0, stream,
                     W_ih, W_hh, W_fc, W_init_h, W_init_c, features,
                     W_ih_b, W_hh_b, W_fc_b, Wih0_b, Wic0_b, feat_b,
                     embed_table, captions, emb_b);

  // ---- gx + h0 + c0 in one dispatch ----
  hipLaunchKernelGGL(gemm_combo, dim3(528), dim3(256), 0, stream,
                     emb_b, W_ih_b, b_ih, b_hh, gx_b,
                     feat_b, Wih0_b, b_init_h, h_all,
                     Wic0_b, b_init_c, c_f32);

  // ---- persistent recurrence (cooperative launch, custom barrier) ----
  {
    void* args[] = {(void*)&W_hh_b, (void*)&gx_b, (void*)&c_f32,
                    (void*)&h_all, (void*)&ctr};
    hipLaunchCooperativeKernel((void*)lstm_seq, dim3(H_ / 4), dim3(512),
                               args, 0, stream);
  }

  // ---- final FC: out = sigmoid(h_all[1..32] @ W_fc^T + b_fc) ----
  hipLaunchKernelGGL((mfma_gemm128<1, 0>), dim3(T_ * B_ / 128, (V_ + 127) / 128), dim3(256), 0, stream,
                     h_all + (size_t)B_ * H_, W_fc_b, b_fc, (const float*)nullptr,
                     (void*)out, T_ * B_, V_, H_);
}